// Round 1
// baseline (2386.827 us; speedup 1.0000x reference)
//
#include <hip/hip_runtime.h>
#include <hip/hip_bf16.h>
#include <math.h>

// Problem constants (from reference)
#define OS 7
constexpr int CCH  = 480;          // I3D_NCH
constexpr int TT   = 4;
constexpr int FY   = 45;
constexpr int FX   = 80;
constexpr int BNB  = 16;           // batch
constexpr int SN   = 32;           // boxes per batch
constexpr int NROI = BNB * SN;     // 512
constexpr int DIN  = CCH * OS * OS;// 23520
constexpr int NDF_ = 1024;
constexpr int NC   = 50;
constexpr float SCALE_X = 80.0f / 1280.0f;  // 0.0625
constexpr float SCALE_Y = 45.0f / 720.0f;   // 0.0625

// ---------------------------------------------------------------------------
// Kernel 1: ROI-align (sampling_ratio=1, aligned=True) on the t=3 slice.
// One block per ROI. Output layout pooled[r][c*49 + py*7 + px] (w_vis K-order).
// ---------------------------------------------------------------------------
__global__ __launch_bounds__(256) void roi_kernel(
    const float* __restrict__ zvis,     // [16,480,4,45,80]
    const float* __restrict__ bboxs,    // [16,32,4]
    float* __restrict__ pooled)         // [512, 23520]
{
    const int r = blockIdx.x;           // 0..511
    const int b = r / SN;
    const int tid = threadIdx.x;

    const float x1 = bboxs[r * 4 + 0] * SCALE_X - 0.5f;
    const float y1 = bboxs[r * 4 + 1] * SCALE_Y - 0.5f;
    const float x2 = bboxs[r * 4 + 2] * SCALE_X - 0.5f;
    const float y2 = bboxs[r * 4 + 3] * SCALE_Y - 0.5f;
    const float bw = (x2 - x1) / (float)OS;
    const float bh = (y2 - y1) / (float)OS;

    __shared__ int   s_yl[OS], s_yh[OS], s_xl[OS], s_xh[OS];
    __shared__ float s_ly[OS], s_lx[OS], s_vy[OS], s_vx[OS];

    if (tid < OS) {
        float y = y1 + ((float)tid + 0.5f) * bh;
        float v = (y > -1.0f && y < (float)FY) ? 1.0f : 0.0f;
        float yc = fminf(fmaxf(y, 0.0f), (float)(FY - 1));
        int yl = (int)floorf(yc);
        s_yl[tid] = yl;
        s_yh[tid] = min(yl + 1, FY - 1);
        s_ly[tid] = yc - (float)yl;
        s_vy[tid] = v;
    } else if (tid < 2 * OS) {
        int i = tid - OS;
        float x = x1 + ((float)i + 0.5f) * bw;
        float v = (x > -1.0f && x < (float)FX) ? 1.0f : 0.0f;
        float xc = fminf(fmaxf(x, 0.0f), (float)(FX - 1));
        int xl = (int)floorf(xc);
        s_xl[i] = xl;
        s_xh[i] = min(xl + 1, FX - 1);
        s_lx[i] = xc - (float)xl;
        s_vx[i] = v;
    }
    __syncthreads();

    float* outr = pooled + (size_t)r * DIN;
    for (int idx = tid; idx < DIN; idx += blockDim.x) {
        int c   = idx / 49;
        int pos = idx - c * 49;
        int py  = pos / 7;
        int px  = pos - py * 7;
        const float* f = zvis + (((size_t)(b * CCH + c)) * TT + (TT - 1)) * (FY * FX);
        int yl = s_yl[py], yh = s_yh[py], xl = s_xl[px], xh = s_xh[px];
        float ly = s_ly[py], lx = s_lx[px];
        float hy = 1.0f - ly, hx = 1.0f - lx;
        float v = s_vy[py] * s_vx[px];
        float f00 = f[yl * FX + xl];
        float f01 = f[yl * FX + xh];
        float f10 = f[yh * FX + xl];
        float f11 = f[yh * FX + xh];
        outr[idx] = (f00 * hy * hx + f01 * hy * lx + f10 * ly * hx + f11 * ly * lx) * v;
    }
}

// ---------------------------------------------------------------------------
// Kernel 2: Z = pooled @ w_vis^T + b_vis + norms*w_spc + b_spc
// TN gemm: both operands K-contiguous. 64x64 tile, BK=16, 256 thr, 4x4/thread.
// ---------------------------------------------------------------------------
constexpr int BM = 64, BN = 64, BK = 16;

__global__ __launch_bounds__(256) void gemm_kernel(
    const float* __restrict__ A,        // pooled [512, 23520]
    const float* __restrict__ W,        // w_vis  [1024, 23520]
    const float* __restrict__ b_vis,    // [1024]
    const float* __restrict__ norms,    // [512]
    const float* __restrict__ w_spc,    // [1024]
    const float* __restrict__ b_spc,    // [1024]
    float* __restrict__ Z)              // [512, 1024]
{
    __shared__ float sA[BK][BM];
    __shared__ float sB[BK][BN];

    const int tid = threadIdx.x;
    const int m0 = blockIdx.y * BM;
    const int n0 = blockIdx.x * BN;
    const int tx = tid & 15;
    const int ty = tid >> 4;

    float acc[4][4] = {};

    for (int k0 = 0; k0 < DIN; k0 += BK) {
        #pragma unroll
        for (int i = 0; i < 4; i++) {
            int lin = tid + i * 256;
            int k = lin & 15;
            int m = lin >> 4;
            sA[k][m] = A[(size_t)(m0 + m) * DIN + k0 + k];
            sB[k][m] = W[(size_t)(n0 + m) * DIN + k0 + k];
        }
        __syncthreads();
        #pragma unroll
        for (int k = 0; k < BK; k++) {
            float a[4], bb[4];
            #pragma unroll
            for (int i = 0; i < 4; i++) a[i] = sA[k][ty * 4 + i];
            #pragma unroll
            for (int j = 0; j < 4; j++) bb[j] = sB[k][tx * 4 + j];
            #pragma unroll
            for (int i = 0; i < 4; i++)
                #pragma unroll
                for (int j = 0; j < 4; j++)
                    acc[i][j] += a[i] * bb[j];
        }
        __syncthreads();
    }

    #pragma unroll
    for (int i = 0; i < 4; i++) {
        int m = m0 + ty * 4 + i;
        float nm = norms[m];
        #pragma unroll
        for (int j = 0; j < 4; j++) {
            int n = n0 + tx * 4 + j;
            Z[(size_t)m * NDF_ + n] = acc[i][j] + b_vis[n] + nm * w_spc[n] + b_spc[n];
        }
    }
}

// ---------------------------------------------------------------------------
// Kernel 3: distances to 50 centroids, s = (1+dist)^-1 normalized, argmax.
// One block (4 waves) per row.
// ---------------------------------------------------------------------------
__global__ __launch_bounds__(256) void cluster_kernel(
    const float* __restrict__ Z,        // [512, 1024]
    const float* __restrict__ cent,     // [50, 1024]
    float* __restrict__ S,              // [512, 50]
    float* __restrict__ Cc)             // [512] (argmax as float)
{
    const int r = blockIdx.x;
    const int tid = threadIdx.x;
    __shared__ float sz[NDF_];
    __shared__ float sd[NC];

    for (int d = tid; d < NDF_; d += 256) sz[d] = Z[(size_t)r * NDF_ + d];
    __syncthreads();

    const int wave = tid >> 6;
    const int lane = tid & 63;
    for (int k = wave; k < NC; k += 4) {
        float sum = 0.0f;
        const float* ck = cent + (size_t)k * NDF_;
        for (int d = lane; d < NDF_; d += 64) {
            float df = sz[d] - ck[d];
            sum += df * df;
        }
        #pragma unroll
        for (int off = 32; off > 0; off >>= 1) sum += __shfl_down(sum, off, 64);
        if (lane == 0) sd[k] = 1.0f / (1.0f + sqrtf(sum));
    }
    __syncthreads();

    if (tid == 0) {
        float tot = 0.0f;
        for (int k = 0; k < NC; k++) tot += sd[k];
        float inv = 1.0f / tot;
        float best = -1.0f;
        int bi = 0;
        for (int k = 0; k < NC; k++) {
            float sv = sd[k] * inv;
            S[(size_t)r * NC + k] = sv;
            if (sv > best) { best = sv; bi = k; }
        }
        Cc[r] = (float)bi;
    }
}

// ---------------------------------------------------------------------------
extern "C" void kernel_launch(void* const* d_in, const int* in_sizes, int n_in,
                              void* d_out, int out_size, void* d_ws, size_t ws_size,
                              hipStream_t stream)
{
    const float* z_vis     = (const float*)d_in[0];
    const float* bboxs     = (const float*)d_in[1];
    const float* norms     = (const float*)d_in[2];
    const float* w_vis     = (const float*)d_in[3];
    const float* b_vis     = (const float*)d_in[4];
    const float* w_spc     = (const float*)d_in[5];
    const float* b_spc     = (const float*)d_in[6];
    const float* centroids = (const float*)d_in[7];

    float* pooled = (float*)d_ws;                        // 512*23520*4 = ~48.2 MB

    float* z_out = (float*)d_out;                        // [512,1024]
    float* s_out = z_out + (size_t)NROI * NDF_;          // [512,50]
    float* c_out = s_out + (size_t)NROI * NC;            // [512]

    roi_kernel<<<NROI, 256, 0, stream>>>(z_vis, bboxs, pooled);

    dim3 ggrid(NDF_ / BN, NROI / BM);
    gemm_kernel<<<ggrid, 256, 0, stream>>>(pooled, w_vis, b_vis, norms, w_spc, b_spc, z_out);

    cluster_kernel<<<NROI, 256, 0, stream>>>(z_out, centroids, s_out, c_out);
}

// Round 2
// 765.672 us; speedup vs baseline: 3.1173x; 3.1173x over previous
//
#include <hip/hip_runtime.h>
#include <math.h>

typedef _Float16 half8 __attribute__((ext_vector_type(8)));
typedef float floatx4 __attribute__((ext_vector_type(4)));

constexpr int CCH = 480, TT = 4, FY = 45, FX = 80;
constexpr int SN = 32, NROI = 512;
constexpr int KDIM = CCH * 49;      // 23520
constexpr int NDF_ = 1024, NC = 50;
constexpr float SCALE_X = 80.0f / 1280.0f;
constexpr float SCALE_Y = 45.0f / 720.0f;

constexpr int BM = 128, BN = 128, BK = 32;
constexpr int SK = 15;
constexpr int ITERS = (KDIM / BK) / SK;   // 49
static_assert(SK * ITERS * BK == KDIM, "split-K must tile K exactly");

// ---------------------------------------------------------------------------
// ROI-align -> exact fp16 hi/lo split (x = hi + lo/2048), layout [r][c*49+pos]
// ---------------------------------------------------------------------------
__global__ __launch_bounds__(256) void roi_split_kernel(
    const float* __restrict__ zvis,     // [16,480,4,45,80]
    const float* __restrict__ bboxs,    // [16,32,4]
    _Float16* __restrict__ phi,         // [512, 23520]
    _Float16* __restrict__ plo)         // [512, 23520]
{
    const int r = blockIdx.x;
    const int b = r >> 5;               // r / SN
    const int tid = threadIdx.x;

    __shared__ float s_w[49][4];
    __shared__ int   s_o[49][4];

    if (tid < 49) {
        const float x1 = bboxs[r * 4 + 0] * SCALE_X - 0.5f;
        const float y1 = bboxs[r * 4 + 1] * SCALE_Y - 0.5f;
        const float x2 = bboxs[r * 4 + 2] * SCALE_X - 0.5f;
        const float y2 = bboxs[r * 4 + 3] * SCALE_Y - 0.5f;
        const float bw = (x2 - x1) / 7.0f;
        const float bh = (y2 - y1) / 7.0f;
        const int py = tid / 7, px = tid % 7;
        float y = y1 + ((float)py + 0.5f) * bh;
        float x = x1 + ((float)px + 0.5f) * bw;
        float v = ((y > -1.0f && y < (float)FY) && (x > -1.0f && x < (float)FX)) ? 1.0f : 0.0f;
        float yc = fminf(fmaxf(y, 0.0f), (float)(FY - 1));
        float xc = fminf(fmaxf(x, 0.0f), (float)(FX - 1));
        int yl = (int)floorf(yc);
        int xl = (int)floorf(xc);
        int yh = min(yl + 1, FY - 1);
        int xh = min(xl + 1, FX - 1);
        float ly = yc - (float)yl, lx = xc - (float)xl;
        float hy = 1.0f - ly, hx = 1.0f - lx;
        s_o[tid][0] = yl * FX + xl;
        s_o[tid][1] = yl * FX + xh;
        s_o[tid][2] = yh * FX + xl;
        s_o[tid][3] = yh * FX + xh;
        s_w[tid][0] = hy * hx * v;
        s_w[tid][1] = hy * lx * v;
        s_w[tid][2] = ly * hx * v;
        s_w[tid][3] = ly * lx * v;
    }
    __syncthreads();

    if (tid >= 245) return;             // 5 c-groups x 49 positions
    const int pos = tid % 49;
    const int cb  = tid / 49;

    const float w0 = s_w[pos][0], w1 = s_w[pos][1], w2 = s_w[pos][2], w3 = s_w[pos][3];
    const int   o0 = s_o[pos][0], o1 = s_o[pos][1], o2 = s_o[pos][2], o3 = s_o[pos][3];

    for (int c = cb; c < CCH; c += 5) {
        const float* f = zvis + (((size_t)(b * CCH + c)) * TT + (TT - 1)) * (FY * FX);
        float val = f[o0] * w0 + f[o1] * w1 + f[o2] * w2 + f[o3] * w3;
        _Float16 hi = (_Float16)val;
        _Float16 lo = (_Float16)((val - (float)hi) * 2048.0f);
        size_t oidx = (size_t)r * KDIM + c * 49 + pos;
        phi[oidx] = hi;
        plo[oidx] = lo;
    }
}

// ---------------------------------------------------------------------------
// Z bias init: Z[m][n] = b_vis[n] + norms[m]*w_spc[n] + b_spc[n]
// ---------------------------------------------------------------------------
__global__ __launch_bounds__(256) void bias_init_kernel(
    const float* __restrict__ b_vis, const float* __restrict__ norms,
    const float* __restrict__ w_spc, const float* __restrict__ b_spc,
    float* __restrict__ Z)
{
    const int m = blockIdx.x;
    const int n = threadIdx.x * 4;
    const float nm = norms[m];
    float4 bv = *(const float4*)(b_vis + n);
    float4 ws = *(const float4*)(w_spc + n);
    float4 bs = *(const float4*)(b_spc + n);
    float4 o;
    o.x = bv.x + nm * ws.x + bs.x;
    o.y = bv.y + nm * ws.y + bs.y;
    o.z = bv.z + nm * ws.z + bs.z;
    o.w = bv.w + nm * ws.w + bs.w;
    *(float4*)(Z + (size_t)m * NDF_ + n) = o;
}

// ---------------------------------------------------------------------------
// Split-K MFMA GEMM, 3-term fp16 error compensation (~fp32 accuracy).
// Z += A @ W^T, A[512][23520] (fp16 hi/lo), W[1024][23520] fp32 (split inline).
// ---------------------------------------------------------------------------
__device__ __forceinline__ void async_cp16(const void* g, void* l) {
    __builtin_amdgcn_global_load_lds(
        (const __attribute__((address_space(1))) void*)g,
        (__attribute__((address_space(3))) void*)l, 16, 0, 0);
}

__global__ __launch_bounds__(256, 2) void gemm3_kernel(
    const _Float16* __restrict__ Ahi, const _Float16* __restrict__ Alo,
    const float* __restrict__ W, float* __restrict__ Z)
{
    __shared__ __align__(16) _Float16 sAh[BM * BK];
    __shared__ __align__(16) _Float16 sAl[BM * BK];
    __shared__ __align__(16) _Float16 sBh[BN * BK];
    __shared__ __align__(16) _Float16 sBl[BN * BK];

    const int tid  = threadIdx.x;
    const int wave = tid >> 6;
    const int lane = tid & 63;
    const int n0 = blockIdx.x * BN;
    const int m0 = blockIdx.y * BM;
    const int kz = blockIdx.z;

    floatx4 ach[4][4], acm[4][4];
    #pragma unroll
    for (int i = 0; i < 4; ++i)
        #pragma unroll
        for (int j = 0; j < 4; ++j) {
            ach[i][j] = (floatx4){0.f, 0.f, 0.f, 0.f};
            acm[i][j] = (floatx4){0.f, 0.f, 0.f, 0.f};
        }

    // A staging map: chunk = 16 rows x 32 elems (1 KB); lane -> row l>>2, col (l&3)*8
    const int chunk = wave * 2;
    const int arow0 = chunk * 16 + (lane >> 2);
    const int acol  = (lane & 3) * 8;

    // B staging map: 2 threads per row, 16 fp32 each
    const int brow = tid >> 1;
    const int bkc  = (tid & 1) * 16;

    // wave tile: 2x2 waves of 64x64
    const int wr = (wave >> 1) * 64;
    const int wc = (wave & 1) * 64;
    const int frow = lane & 15;
    const int ko   = (lane >> 4) * 8;

    for (int it = 0; it < ITERS; ++it) {
        const int k0 = (kz * ITERS + it) * BK;

        // async A hi/lo -> LDS (2 chunks per wave per buffer)
        #pragma unroll
        for (int i = 0; i < 2; ++i) {
            const size_t go = (size_t)(m0 + arow0 + i * 16) * KDIM + k0 + acol;
            async_cp16(Ahi + go, (void*)(sAh + (chunk + i) * 512));
            async_cp16(Alo + go, (void*)(sAl + (chunk + i) * 512));
        }

        // B: 16 fp32 -> fp16 hi/lo
        const float* gW = W + (size_t)(n0 + brow) * KDIM + k0 + bkc;
        float xs[16];
        *(float4*)(xs + 0)  = *(const float4*)(gW + 0);
        *(float4*)(xs + 4)  = *(const float4*)(gW + 4);
        *(float4*)(xs + 8)  = *(const float4*)(gW + 8);
        *(float4*)(xs + 12) = *(const float4*)(gW + 12);
        _Float16 hs[16], ls[16];
        #pragma unroll
        for (int e = 0; e < 16; ++e) {
            _Float16 h = (_Float16)xs[e];
            hs[e] = h;
            ls[e] = (_Float16)((xs[e] - (float)h) * 2048.0f);
        }
        *(half8*)(sBh + brow * 32 + bkc)     = *(half8*)(hs);
        *(half8*)(sBh + brow * 32 + bkc + 8) = *(half8*)(hs + 8);
        *(half8*)(sBl + brow * 32 + bkc)     = *(half8*)(ls);
        *(half8*)(sBl + brow * 32 + bkc + 8) = *(half8*)(ls + 8);

        __syncthreads();

        half8 bh[4], bl[4];
        #pragma unroll
        for (int ni = 0; ni < 4; ++ni) {
            const int n_l = wc + ni * 16 + frow;
            bh[ni] = *(const half8*)(sBh + n_l * 32 + ko);
            bl[ni] = *(const half8*)(sBl + n_l * 32 + ko);
        }
        #pragma unroll
        for (int mi = 0; mi < 4; ++mi) {
            const int m_l = wr + mi * 16 + frow;
            half8 ah = *(const half8*)(sAh + m_l * 32 + ko);
            half8 al = *(const half8*)(sAl + m_l * 32 + ko);
            #pragma unroll
            for (int ni = 0; ni < 4; ++ni) {
                ach[mi][ni] = __builtin_amdgcn_mfma_f32_16x16x32_f16(ah, bh[ni], ach[mi][ni], 0, 0, 0);
                acm[mi][ni] = __builtin_amdgcn_mfma_f32_16x16x32_f16(ah, bl[ni], acm[mi][ni], 0, 0, 0);
                acm[mi][ni] = __builtin_amdgcn_mfma_f32_16x16x32_f16(al, bh[ni], acm[mi][ni], 0, 0, 0);
            }
        }
        __syncthreads();
    }

    // epilogue: C/D layout col=lane&15 (n), row=(lane>>4)*4+reg (m)
    const float inv2048 = 1.0f / 2048.0f;
    #pragma unroll
    for (int mi = 0; mi < 4; ++mi)
        #pragma unroll
        for (int ni = 0; ni < 4; ++ni)
            #pragma unroll
            for (int rr = 0; rr < 4; ++rr) {
                int gm = m0 + wr + mi * 16 + (lane >> 4) * 4 + rr;
                int gn = n0 + wc + ni * 16 + (lane & 15);
                unsafeAtomicAdd(&Z[(size_t)gm * NDF_ + gn],
                                ach[mi][ni][rr] + acm[mi][ni][rr] * inv2048);
            }
}

// ---------------------------------------------------------------------------
// Clustering: dist to 50 centroids, s=(1+dist)^-1 normalized, argmax
// ---------------------------------------------------------------------------
__global__ __launch_bounds__(256) void cluster_kernel(
    const float* __restrict__ Z, const float* __restrict__ cent,
    float* __restrict__ S, float* __restrict__ Cc)
{
    const int r = blockIdx.x;
    const int tid = threadIdx.x;
    __shared__ float sz[NDF_];
    __shared__ float sd[NC];

    for (int d = tid; d < NDF_; d += 256) sz[d] = Z[(size_t)r * NDF_ + d];
    __syncthreads();

    const int wave = tid >> 6;
    const int lane = tid & 63;
    for (int k = wave; k < NC; k += 4) {
        float sum = 0.0f;
        const float* ck = cent + (size_t)k * NDF_;
        for (int d = lane; d < NDF_; d += 64) {
            float df = sz[d] - ck[d];
            sum += df * df;
        }
        #pragma unroll
        for (int off = 32; off > 0; off >>= 1) sum += __shfl_down(sum, off, 64);
        if (lane == 0) sd[k] = 1.0f / (1.0f + sqrtf(sum));
    }
    __syncthreads();

    if (tid == 0) {
        float tot = 0.0f;
        for (int k = 0; k < NC; k++) tot += sd[k];
        float inv = 1.0f / tot;
        float best = -1.0f;
        int bi = 0;
        for (int k = 0; k < NC; k++) {
            float sv = sd[k] * inv;
            S[(size_t)r * NC + k] = sv;
            if (sv > best) { best = sv; bi = k; }
        }
        Cc[r] = (float)bi;
    }
}

// ---------------------------------------------------------------------------
extern "C" void kernel_launch(void* const* d_in, const int* in_sizes, int n_in,
                              void* d_out, int out_size, void* d_ws, size_t ws_size,
                              hipStream_t stream)
{
    const float* z_vis     = (const float*)d_in[0];
    const float* bboxs     = (const float*)d_in[1];
    const float* norms     = (const float*)d_in[2];
    const float* w_vis     = (const float*)d_in[3];
    const float* b_vis     = (const float*)d_in[4];
    const float* w_spc     = (const float*)d_in[5];
    const float* b_spc     = (const float*)d_in[6];
    const float* centroids = (const float*)d_in[7];

    _Float16* phi = (_Float16*)d_ws;                      // 24.1 MB
    _Float16* plo = phi + (size_t)NROI * KDIM;            // 24.1 MB (total 48.2)

    float* z_out = (float*)d_out;                         // [512,1024]
    float* s_out = z_out + (size_t)NROI * NDF_;           // [512,50]
    float* c_out = s_out + (size_t)NROI * NC;             // [512]

    roi_split_kernel<<<NROI, 256, 0, stream>>>(z_vis, bboxs, phi, plo);

    bias_init_kernel<<<NROI, 256, 0, stream>>>(b_vis, norms, w_spc, b_spc, z_out);

    dim3 ggrid(NDF_ / BN, NROI / BM, SK);
    gemm3_kernel<<<ggrid, 256, 0, stream>>>(phi, plo, w_vis, z_out);

    cluster_kernel<<<NROI, 256, 0, stream>>>(z_out, centroids, s_out, c_out);
}